// Round 1
// baseline (4363.681 us; speedup 1.0000x reference)
//
#include <hip/hip_runtime.h>
#include <math.h>

// SpatialGRU: B=64, C=16, L=64, R=64, U=64, D=C+3U=208
// Wavefront over 127 anti-diagonals; 1 launch per diagonal.
// Per cell: 4 blocks (batch-split 16 each), 512 threads.
// Phase A: rr (192 outs) + z gates (256 outs, gate-interleaved packing) from hq=[ht|hl|hd|x]
// Phase B: h_new = tanh(P @ U2) with P = rr .* hu (+x tail), combine with softmax gates.

#define Bsz 64
#define Cc 16
#define Lr 64
#define Rr 64
#define Uu 64
#define KJ 208          // 192 (h part) + 16 (x part)
#define JQ 52           // KJ/4
#define KP 512          // padded output-k count (192 rr + 256 z + 64 dummy)
#define HSTRIDE 212     // hq/P row stride in floats (16B-aligned: 212*4=848)

// ws layout (floats):
#define OFF_W2 0                         // [JQ][KP][4]  = 106496
#define OFF_BA (OFF_W2 + JQ*KP*4)        // [KP]         = 512
#define OFF_U2 (OFF_BA + KP)             // [JQ][64][4]  = 13312
#define OFF_HD (OFF_U2 + JQ*64*4)        // [3][64][4096]= 786432
#define WS_FLOATS (OFF_HD + 3*64*4096)   // total 906752 floats = 3.63 MB

__global__ __launch_bounds__(512) void prep_pack(
    const float* __restrict__ wr_w, const float* __restrict__ wr_b,
    const float* __restrict__ wz_w, const float* __restrict__ wz_b,
    const float* __restrict__ wij_w, const float* __restrict__ U_w,
    float* __restrict__ ws)
{
    int idx = blockIdx.x * blockDim.x + threadIdx.x;
    const int nW2 = JQ * KP * 4;
    if (idx < nW2) {
        int t  = idx & 3;
        int kp = (idx >> 2) % KP;
        int jq = (idx >> 2) / KP;
        int j  = jq * 4 + t;
        float v = 0.f;
        if (j < KJ) {
            if (kp < 192) {
                v = wr_w[kp * KJ + j];
            } else if (kp < 448) {
                int u = (kp - 192) >> 2;
                int g = (kp - 192) & 3;
                v = wz_w[(g * 64 + u) * KJ + j];
            }
        }
        ws[OFF_W2 + idx] = v;
        return;
    }
    idx -= nW2;
    if (idx < KP) {
        float v = 0.f;
        if (idx < 192) v = wr_b[idx];
        else if (idx < 448) {
            int u = (idx - 192) >> 2;
            int g = (idx - 192) & 3;
            v = wz_b[g * 64 + u];
        }
        ws[OFF_BA + idx] = v;
        return;
    }
    idx -= KP;
    if (idx < JQ * 64 * 4) {
        int t  = idx & 3;
        int u  = (idx >> 2) % 64;
        int jq = (idx >> 2) / 64;
        int j  = jq * 4 + t;
        float v;
        if (j < 192) v = U_w[u * 192 + j];
        else         v = wij_w[u * 16 + (j - 192)];
        ws[OFF_U2 + idx] = v;
    }
}

__global__ __launch_bounds__(512) void diag_step(
    int d,
    const float* __restrict__ inp,     // (B,C,L,R)
    const float* __restrict__ wij_b,   // (64,)
    float* __restrict__ ws,
    float* __restrict__ out)
{
    __shared__ __align__(16) float hq_s[16][HSTRIDE];  // [ht(64)|hl(64)|hd(64)|x(16)|pad]
    __shared__ __align__(16) float P_s[16][HSTRIDE];   // rr .* hu, then x tail
    __shared__ float ZH_s[16][64];                     // zl*hl + zt*ht + zd*hd
    __shared__ float ZI_s[16][64];                     // zi

    const int cell = blockIdx.x >> 2;
    const int bq   = blockIdx.x & 3;
    const int lmin = (d > 63) ? (d - 63) : 0;
    const int l    = lmin + cell;
    const int r    = d - l;
    const int b0   = bq * 16;

    const float* W2 = ws + OFF_W2;
    const float* BA = ws + OFF_BA;
    const float* U2 = ws + OFF_U2;
    float* Hd = ws + OFF_HD;
    const float* Hm1 = Hd + ((d + 2) % 3) * 64 * 4096;  // diagonal d-1
    const float* Hm2 = Hd + ((d + 1) % 3) * 64 * 4096;  // diagonal d-2
    float* Hcur      = Hd + (d % 3) * 64 * 4096;

    const int tid = threadIdx.x;

    // ---- stage hq = [h_top | h_left | h_diag | x] for 16 batch rows ----
    for (int i = tid; i < 16 * HSTRIDE; i += 512) {
        int bb = i / HSTRIDE, j = i % HSTRIDE;
        int b = b0 + bb;
        float v = 0.f;
        if (j < 64) {
            if (l > 0) v = Hm1[r * 4096 + b * 64 + j];                     // h_top = h(l-1, r)
        } else if (j < 128) {
            if (r > 0) v = Hm1[(r - 1) * 4096 + b * 64 + (j - 64)];        // h_left = h(l, r-1)
        } else if (j < 192) {
            if (l > 0 && r > 0) v = Hm2[(r - 1) * 4096 + b * 64 + (j - 128)]; // h_diag
        } else if (j < KJ) {
            v = inp[((b * Cc + (j - 192)) * Lr + l) * Rr + r];             // x(l,r,b,c)
        }
        hq_s[bb][j] = v;
    }
    __syncthreads();

    const int wv = tid >> 6, lane = tid & 63;

    // ---- phase A: 8 waves x 2 jobs; job = (k-chunk of 64) x (bb half of 8) ----
    for (int jj = 0; jj < 2; ++jj) {
        const int job = wv * 2 + jj;
        const int kc = job >> 1, bh = job & 1;
        const int kp = kc * 64 + lane;

        float acc[8] = {0.f, 0.f, 0.f, 0.f, 0.f, 0.f, 0.f, 0.f};
        for (int jq = 0; jq < JQ; ++jq) {
            const float4 w4 = *(const float4*)&W2[((jq * KP) + kp) * 4];
            #pragma unroll
            for (int i = 0; i < 8; ++i) {
                const int bb = bh * 8 + i;
                const float4 h4 = *(const float4*)&hq_s[bb][jq * 4];
                acc[i] = fmaf(w4.x, h4.x, acc[i]);
                acc[i] = fmaf(w4.y, h4.y, acc[i]);
                acc[i] = fmaf(w4.z, h4.z, acc[i]);
                acc[i] = fmaf(w4.w, h4.w, acc[i]);
            }
        }
        const float bias = BA[kp];

        if (kp < 192) {
            // rr path: P = sigmoid(pre) * hu;  hu = [hl | ht | hd]
            #pragma unroll
            for (int i = 0; i < 8; ++i) {
                const int bb = bh * 8 + i;
                float rr = 1.f / (1.f + __expf(-(acc[i] + bias)));
                float hu = (kp < 64) ? hq_s[bb][64 + kp]
                         : (kp < 128) ? hq_s[bb][kp - 64]
                         : hq_s[bb][kp];
                P_s[bb][kp] = rr * hu;
            }
        } else if (kp < 448) {
            // z path: gates interleaved in lane quads: g = lane&3, order [i,l,t,d]
            const int g = lane & 3;
            const int u = (kp - 192) >> 2;
            #pragma unroll
            for (int i = 0; i < 8; ++i) {
                const int bb = bh * 8 + i;
                float zp = acc[i] + bias;
                float m = fmaxf(zp, __shfl_xor(zp, 1, 64));
                m = fmaxf(m, __shfl_xor(m, 2, 64));
                float e = __expf(zp - m);
                float s = e + __shfl_xor(e, 1, 64);
                s = s + __shfl_xor(s, 2, 64);
                float gate = e / s;
                if (g == 0) ZI_s[bb][u] = gate;
                float t = 0.f;
                if (g == 1)      t = gate * hq_s[bb][64 + u];  // zl * h_left
                else if (g == 2) t = gate * hq_s[bb][u];       // zt * h_top
                else if (g == 3) t = gate * hq_s[bb][128 + u]; // zd * h_diag
                float s3 = t + __shfl_xor(t, 1, 64);
                s3 = s3 + __shfl_xor(s3, 2, 64);
                if (g == 0) ZH_s[bb][u] = s3;
            }
        } else {
            // dummy k-chunk: copy x tail into P so phase B dot covers wij part
            if (lane < 16) {
                #pragma unroll
                for (int i = 0; i < 8; ++i) {
                    const int bb = bh * 8 + i;
                    P_s[bb][192 + lane] = hq_s[bb][192 + lane];
                }
            }
        }
    }
    __syncthreads();

    // ---- phase B: h_new = tanh(P @ U2row + wij_b); combine; write ring ----
    {
        const int u = lane;
        float acc2[2] = {0.f, 0.f};
        for (int jq = 0; jq < JQ; ++jq) {
            const float4 w4 = *(const float4*)&U2[((jq * 64) + u) * 4];
            #pragma unroll
            for (int i = 0; i < 2; ++i) {
                const int bb = wv * 2 + i;
                const float4 h4 = *(const float4*)&P_s[bb][jq * 4];
                acc2[i] = fmaf(w4.x, h4.x, acc2[i]);
                acc2[i] = fmaf(w4.y, h4.y, acc2[i]);
                acc2[i] = fmaf(w4.z, h4.z, acc2[i]);
                acc2[i] = fmaf(w4.w, h4.w, acc2[i]);
            }
        }
        #pragma unroll
        for (int i = 0; i < 2; ++i) {
            const int bb = wv * 2 + i;
            const int b = b0 + bb;
            float hn = tanhf(acc2[i] + wij_b[u]);
            float h = ZH_s[bb][u] + ZI_s[bb][u] * hn;
            Hcur[r * 4096 + b * 64 + u] = h;
            if (l == 63 && r == 63) out[b * 64 + u] = h;
        }
    }
}

extern "C" void kernel_launch(void* const* d_in, const int* in_sizes, int n_in,
                              void* d_out, int out_size, void* d_ws, size_t ws_size,
                              hipStream_t stream)
{
    const float* inp   = (const float*)d_in[0];
    const float* wr_w  = (const float*)d_in[1];
    const float* wr_b  = (const float*)d_in[2];
    const float* wz_w  = (const float*)d_in[3];
    const float* wz_b  = (const float*)d_in[4];
    const float* wij_w = (const float*)d_in[5];
    const float* wij_b = (const float*)d_in[6];
    const float* U_w   = (const float*)d_in[7];
    float* ws  = (float*)d_ws;
    float* out = (float*)d_out;

    // pack weights: W2 (gate-interleaved z rows), BA bias, U2 (U_w|wij_w)
    prep_pack<<<235, 512, 0, stream>>>(wr_w, wr_b, wz_w, wz_b, wij_w, U_w, ws);

    for (int d = 0; d < 127; ++d) {
        int lmin = (d > 63) ? (d - 63) : 0;
        int lmax = (d < 63) ? d : 63;
        int nd = lmax - lmin + 1;
        diag_step<<<nd * 4, 512, 0, stream>>>(d, inp, wij_b, ws, out);
    }
}